// Round 9
// baseline (287.124 us; speedup 1.0000x reference)
//
#include <hip/hip_runtime.h>
#include <math.h>

typedef _Float16 half_t;
typedef __attribute__((ext_vector_type(8))) _Float16 half8;
typedef __attribute__((ext_vector_type(4))) _Float16 half4;
typedef __attribute__((ext_vector_type(4))) float floatx4;

#define TDIM 36
#define PDIM 161        // 2*80+1 atoms
#define NCOL 50
#define DHALF 25        // columns per block (d split across 2 blocks per batch item)
#define NITER 100
#define PITER8 50       // power steps on G^8 == 400 on G (proven config)

// R8 per-wave structure, split into 2 blocks/CU for barrier desync.
// Grid: 512 blocks x 384 threads (6 waves). block = (batch b, column-half dh).
// phase A: M=48,N=32,K=192 (6 ks), 6 waves = 3 mt x 2 nt, D hi/lo (12 MFMA/wave)
// phase B: M=192 (12 pt incl ghost pt=11), N=32, K=64; wave g owns pt {g,g+6},
//          both stripes; D^T hi ONLY -> 8 MFMA/wave. Same VGPR profile as R8 (~80).
#define NKA 6
#define GSTR 44
#define SPS 196         // Df (fp32) row stride (dwords)

// row strides in BYTES
#define YROW 384        // y^T [32][192] half
#define RROW 128        // R^T [32][64] half

// XOR swizzle: spread same-column reads across 8 rows -> 8 distinct 16B slots
#define SWZ(row, byteoff) ((byteoff) ^ (((row) & 7) << 4))

// ---- byte-offset LDS map: 48,544 B per block -> 2 blocks/CU (97 KB) ----
#define BY_Y    0                      // 12,288
#define BY_R    12288                  //  4,096
#define BY_DFX  16384                  // 11,840 (Df tail spill: Df = 28,224 B total)
#define BY_LRTH 28224                  //  1,288
#define BY_SC   29512                  //     16
#define BY_GS   29536                  //  6,336 (16B aligned)
#define BY_G2   35872                  //  6,336 (holds G^2, later G^8)
#define BY_G4   42208                  //  6,336
#define LDS_TOTAL 48544
// setup alias: Df fp32 [36][196] = 28,224 B over Y+R+DFX (Y+R re-zeroed before loop)

#define MFMA16 __builtin_amdgcn_mfma_f32_16x16x32_f16

__global__ __launch_bounds__(384, 4)
void dan_kernel(const float* __restrict__ xin, const float* __restrict__ rho,
                const float* __restrict__ theta, float* __restrict__ outC,
                float* __restrict__ outDic, float* __restrict__ outR)
{
  extern __shared__ char smc[];
  float*  sc   = (float*)(smc + BY_SC);
  float*  Gs   = (float*)(smc + BY_GS);
  float*  G2   = (float*)(smc + BY_G2);
  float*  G4   = (float*)(smc + BY_G4);
  float*  Df   = (float*)(smc + BY_Y);    // setup alias (28,224 B)
  float*  lrth = (float*)(smc + BY_LRTH); // [161] lr, [161] th (setup only)

  const int tid = threadIdx.x;
  const int blk = blockIdx.x;
  const int b  = blk >> 1;              // batch item
  const int dh = blk & 1;               // column half: cols dh*25 .. dh*25+24
  const int wave = tid >> 6, lane = tid & 63;
  const int q = lane >> 4, ln = lane & 15;

  // ---- A. zero all LDS (pads must be 0)
  {
    unsigned int* z = (unsigned int*)smc;
    for (int i = tid; i < LDS_TOTAL / 4; i += 384) z[i] = 0u;
  }
  __syncthreads();

  // ---- B0. per-atom lr/th (161 threads, 2 transcendentals each)
  if (tid >= 1 && tid < PDIM) {
    const bool is_sin = tid > 80;
    const int n = is_sin ? (tid - 81) : (tid - 1);
    lrth[tid]       = logf(0.001f + 1.149f / (1.0f + expf(-rho[n])));
    lrth[161 + tid] = 3.14159265358979f / (1.0f + expf(-theta[n]));
  }
  __syncthreads();

  // ---- B1. raw dictionary, parallel over all (t,p) jobs
  for (int i = tid; i < TDIM * PDIM; i += 384) {
    const int t = i / PDIM, p = i - t * PDIM;
    float val;
    if (p == 0) {
      val = 1.0f;
    } else {
      const float ft = (float)t;
      const float e = expf(ft * lrth[p]);
      const float ang = ft * lrth[161 + p];
      val = e * (p > 80 ? sinf(ang) : cosf(ang));
    }
    Df[t * SPS + p] = val;
  }
  __syncthreads();

  // ---- B2. column-normalize (atoms 1..160)
  if (tid >= 1 && tid < PDIM) {
    float s2 = 0.0f;
    for (int t = 0; t < TDIM; ++t) {
      const float v = Df[t * SPS + tid];
      s2 += v * v;
    }
    const float inv = 1.0f / sqrtf(s2);
    for (int t = 0; t < TDIM; ++t) Df[t * SPS + tid] *= inv;
  }
  __syncthreads();

  // ---- C. Gram -> Gs ; dic out ; load ALL MFMA fragments to registers
  for (int job = tid; job < 666; job += 384) {   // 666 = 36*37/2
    int i = 0, rem = job;
    while (rem >= TDIM - i) { rem -= TDIM - i; ++i; }
    const int j = i + rem;
    const float4* ri = (const float4*)(Df + i * SPS);
    const float4* rj = (const float4*)(Df + j * SPS);
    float a = 0.0f;
    #pragma unroll 7
    for (int k = 0; k < SPS / 4; ++k) {
      const float4 x = ri[k], y = rj[k];
      a += x.x * y.x + x.y * y.y + x.z * y.z + x.w * y.w;
    }
    Gs[i * GSTR + j] = a;
    Gs[j * GSTR + i] = a;
  }
  if (blk == 0) {
    for (int i = tid; i < TDIM * PDIM; i += 384) {
      const int t = i / PDIM, p = i - t * PDIM;
      outDic[i] = Df[t * SPS + p];
    }
  }

  // ownership maps
  const int mtA = wave >> 1;            // phase A: 3 mt x 2 nt, one tile per wave
  const int ntA = wave & 1;
  const int g = wave;                   // phase B: pt in {g, g+6}; both stripes

  // phase-A A-fragments (D hi/lo); rows >= 36 are zero
  half8 DhF[NKA], DlF[NKA];
  {
    const int row = 16 * mtA + ln;
    #pragma unroll
    for (int ks = 0; ks < NKA; ++ks) {
      half8 hh = {0,0,0,0,0,0,0,0}, ll = {0,0,0,0,0,0,0,0};
      if (row < TDIM) {
        const float4 f0 = *(const float4*)(Df + row * SPS + 32 * ks + 8 * q);
        const float4 f1 = *(const float4*)(Df + row * SPS + 32 * ks + 8 * q + 4);
        const float fa[8] = {f0.x, f0.y, f0.z, f0.w, f1.x, f1.y, f1.z, f1.w};
        #pragma unroll
        for (int e = 0; e < 8; ++e) {
          const half_t h2 = (half_t)fa[e];
          hh[e] = h2;
          ll[e] = (half_t)(fa[e] - (float)h2);
        }
      }
      DhF[ks] = hh;
      DlF[ks] = ll;
    }
  }
  // phase-B A-fragments (D^T hi ONLY); atoms >= 161 are zero cols of Df
  half8 DtH[2][2];                      // [k][ks]
  #pragma unroll
  for (int k = 0; k < 2; ++k) {
    const int atom = 16 * (g + 6 * k) + ln;         // 0..191
    #pragma unroll
    for (int ks = 0; ks < 2; ++ks) {
      half8 hh;
      #pragma unroll
      for (int e = 0; e < 8; ++e) {
        const int t = 32 * ks + 8 * q + e;
        const float v = (t < TDIM) ? Df[t * SPS + atom] : 0.0f;
        hh[e] = (half_t)v;
      }
      DtH[k][ks] = hh;
    }
  }
  // static Y (fp32) at phase-A C positions (this block's 25-column half)
  float yA[4];
  {
    const float* xb = xin + b * TDIM * NCOL;
    const int c = 16 * ntA + ln;        // 0..31 local
    #pragma unroll
    for (int r = 0; r < 4; ++r) {
      const int t = 16 * mtA + 4 * q + r;
      yA[r] = (t < TDIM && c < DHALF) ? xb[t * NCOL + dh * DHALF + c] : 0.0f;
    }
  }
  __syncthreads();

  // ---- C2. G2 = G*G  (pads of all Gram buffers are zero)
  for (int job = tid; job < 666; job += 384) {
    int i = 0, rem = job;
    while (rem >= TDIM - i) { rem -= TDIM - i; ++i; }
    const int j = i + rem;
    const float4* ri = (const float4*)(Gs + i * GSTR);
    const float4* rj = (const float4*)(Gs + j * GSTR);
    float a = 0.0f;
    #pragma unroll
    for (int k = 0; k < GSTR / 4; ++k) {
      const float4 x = ri[k], y = rj[k];
      a += x.x * y.x + x.y * y.y + x.z * y.z + x.w * y.w;
    }
    G2[i * GSTR + j] = a;
    G2[j * GSTR + i] = a;
  }
  __syncthreads();
  // ---- C3. G4 = G2*G2
  for (int job = tid; job < 666; job += 384) {
    int i = 0, rem = job;
    while (rem >= TDIM - i) { rem -= TDIM - i; ++i; }
    const int j = i + rem;
    const float4* ri = (const float4*)(G2 + i * GSTR);
    const float4* rj = (const float4*)(G2 + j * GSTR);
    float a = 0.0f;
    #pragma unroll
    for (int k = 0; k < GSTR / 4; ++k) {
      const float4 x = ri[k], y = rj[k];
      a += x.x * y.x + x.y * y.y + x.z * y.z + x.w * y.w;
    }
    G4[i * GSTR + j] = a;
    G4[j * GSTR + i] = a;
  }
  __syncthreads();
  // ---- C4. G8 = G4*G4 -> overwrite G2 buffer
  for (int job = tid; job < 666; job += 384) {
    int i = 0, rem = job;
    while (rem >= TDIM - i) { rem -= TDIM - i; ++i; }
    const int j = i + rem;
    const float4* ri = (const float4*)(G4 + i * GSTR);
    const float4* rj = (const float4*)(G4 + j * GSTR);
    float a = 0.0f;
    #pragma unroll
    for (int k = 0; k < GSTR / 4; ++k) {
      const float4 x = ri[k], y = rj[k];
      a += x.x * y.x + x.y * y.y + x.z * y.z + x.w * y.w;
    }
    G2[i * GSTR + j] = a;
    G2[j * GSTR + i] = a;
  }
  __syncthreads();

  // ---- D2. wave 0: power iteration on G8 (renorm every iter); waves 1..5 zero Y+R
  if (wave == 0) {
    float g8r[36];
    #pragma unroll
    for (int j = 0; j < 36; ++j) g8r[j] = (lane < 36) ? G2[lane * GSTR + j] : 0.0f;
    float v = (lane < 36) ? 1.0f : 0.0f;
    for (int it = 0; it < PITER8; ++it) {
      const int vi = __float_as_int(v);
      float w0 = 0.0f, w1 = 0.0f, w2 = 0.0f, w3 = 0.0f;
      #pragma unroll
      for (int j = 0; j < 36; j += 4) {
        w0 = fmaf(g8r[j],     __int_as_float(__builtin_amdgcn_readlane(vi, j)),     w0);
        w1 = fmaf(g8r[j + 1], __int_as_float(__builtin_amdgcn_readlane(vi, j + 1)), w1);
        w2 = fmaf(g8r[j + 2], __int_as_float(__builtin_amdgcn_readlane(vi, j + 2)), w2);
        w3 = fmaf(g8r[j + 3], __int_as_float(__builtin_amdgcn_readlane(vi, j + 3)), w3);
      }
      float w = (w0 + w1) + (w2 + w3);
      float s = w * w;
      #pragma unroll
      for (int off = 32; off > 0; off >>= 1) s += __shfl_xor(s, off, 64);
      v = w * rsqrtf(s);
    }
    // Rayleigh on ORIGINAL G (v is unit)
    const int vi = __float_as_int(v);
    float w0 = 0.0f, w1 = 0.0f;
    #pragma unroll
    for (int j = 0; j < 36; j += 2) {
      const float gi0 = (lane < 36) ? Gs[lane * GSTR + j]     : 0.0f;
      const float gi1 = (lane < 36) ? Gs[lane * GSTR + j + 1] : 0.0f;
      w0 = fmaf(gi0, __int_as_float(__builtin_amdgcn_readlane(vi, j)),     w0);
      w1 = fmaf(gi1, __int_as_float(__builtin_amdgcn_readlane(vi, j + 1)), w1);
    }
    float num = v * (w0 + w1);
    #pragma unroll
    for (int off = 32; off > 0; off >>= 1) num += __shfl_xor(num, off, 64);
    if (lane == 0) {
      sc[0] = 1.0f / num;        // L_inv
      sc[1] = 0.1f / num;        // thr = lam_f * L_inv
    }
  } else {
    unsigned int* z = (unsigned int*)smc;
    for (int i = tid - 64; i < (BY_R + 4096) / 4; i += 320) z[i] = 0u;  // Y+R zero
  }
  __syncthreads();
  const float L_inv = sc[0];
  const float thr = sc[1];

  float xR[2][2][4], yR[2][2][4];       // [pt-idx][stripe][r]
  #pragma unroll
  for (int k = 0; k < 2; ++k)
    #pragma unroll
    for (int s = 0; s < 2; ++s)
      #pragma unroll
      for (int r = 0; r < 4; ++r) { xR[k][s][r] = 0.0f; yR[k][s][r] = 0.0f; }

  float tk = 1.0f;

  // ---- F. FISTA loop (R8 body at N=32, 6 waves; 2 desynced blocks per CU)
  for (int it = 0; it < NITER; ++it) {
    // phase A (all 6 waves): R = Y - D y   (M=48, N=32, K=192)
    {
      floatx4 aH0 = {0.f,0.f,0.f,0.f}, aH1 = {0.f,0.f,0.f,0.f};
      floatx4 aL0 = {0.f,0.f,0.f,0.f}, aL1 = {0.f,0.f,0.f,0.f};
      const int n0 = 16 * ntA + ln;
      const char* yrow = smc + BY_Y + n0 * YROW;
      #pragma unroll
      for (int ks = 0; ks < NKA; ++ks) {
        const int kb = (32 * ks + 8 * q) * 2;
        const half8 b0 = *(const half8*)(yrow + SWZ(n0, kb));
        if (ks & 1) {
          aH1 = MFMA16(DhF[ks], b0, aH1, 0, 0, 0);
          aL1 = MFMA16(DlF[ks], b0, aL1, 0, 0, 0);
        } else {
          aH0 = MFMA16(DhF[ks], b0, aH0, 0, 0, 0);
          aL0 = MFMA16(DlF[ks], b0, aL0, 0, 0, 0);
        }
      }
      const int t0 = 16 * mtA + 4 * q;
      half4 hv;
      #pragma unroll
      for (int r = 0; r < 4; ++r)
        hv[r] = (half_t)(yA[r] - ((aH0[r] + aH1[r]) + (aL0[r] + aL1[r])));
      *(half4*)(smc + BY_R + n0 * RROW + SWZ(n0, t0 * 2)) = hv;
    }
    __syncthreads();

    const float tnew = 0.5f * (1.0f + sqrtf(1.0f + 4.0f * tk * tk));
    const float ttf = (tk - 1.0f) / tnew;
    tk = tnew;

    // phase B: w = y + L_inv D^T R ; shrink + momentum  (hi-only D^T)
    // Wave reads both stripes of R (4 b128), reused for its 2 pt tiles.
    {
      half8 rb[2][2];
      #pragma unroll
      for (int s = 0; s < 2; ++s) {
        const int cS = 16 * s + ln;
        const char* rrow = smc + BY_R + cS * RROW;
        rb[s][0] = *(const half8*)(rrow + SWZ(cS, 16 * q));        // t = 8q..8q+7
        rb[s][1] = *(const half8*)(rrow + SWZ(cS, 64 + 16 * q));   // t = 32+8q (pads 0)
      }

      #pragma unroll
      for (int k = 0; k < 2; ++k) {
        const int pt = g + 6 * k;
        const int p0 = 16 * pt + 4 * q;
        #pragma unroll
        for (int s = 0; s < 2; ++s) {
          floatx4 a = {0.f,0.f,0.f,0.f};
          a = MFMA16(DtH[k][0], rb[s][0], a, 0, 0, 0);
          a = MFMA16(DtH[k][1], rb[s][1], a, 0, 0, 0);
          const int cS = 16 * s + ln;
          half4 hv;
          #pragma unroll
          for (int r = 0; r < 4; ++r) {
            const float w = yR[k][s][r] + L_inv * a[r];
            const float cl = fminf(fmaxf(w, -thr), thr);   // v_med3 clamp
            const float xn = w - cl;                        // softshrink
            const float yn = xn + ttf * (xn - xR[k][s][r]);
            xR[k][s][r] = xn;
            yR[k][s][r] = yn;
            hv[r] = (half_t)yn;
          }
          *(half4*)(smc + BY_Y + cS * YROW + SWZ(cS, p0 * 2)) = hv;
        }
      }
    }
    __syncthreads();
  }

  // ---- G. outputs: C = x_fin (ghost atoms masked by p < PDIM; cols by c < DHALF)
  float* Cb = outC + b * PDIM * NCOL + dh * DHALF;
  #pragma unroll
  for (int k = 0; k < 2; ++k) {
    const int pt = g + 6 * k;
    #pragma unroll
    for (int s = 0; s < 2; ++s) {
      const int cS = 16 * s + ln;
      if (cS < DHALF) {
        #pragma unroll
        for (int r = 0; r < 4; ++r) {
          const int p = 16 * pt + 4 * q + r;
          if (p < PDIM) Cb[p * NCOL + cS] = xR[k][s][r];
        }
      }
    }
  }
  // reconst = D @ C : restage x into Y (fp16), rerun phase-A GEMM
  #pragma unroll
  for (int k = 0; k < 2; ++k) {
    const int pt = g + 6 * k;
    const int p0 = 16 * pt + 4 * q;
    #pragma unroll
    for (int s = 0; s < 2; ++s) {
      const int cS = 16 * s + ln;
      half4 hv;
      #pragma unroll
      for (int r = 0; r < 4; ++r) hv[r] = (half_t)xR[k][s][r];
      *(half4*)(smc + BY_Y + cS * YROW + SWZ(cS, p0 * 2)) = hv;
    }
  }
  __syncthreads();
  {
    floatx4 aH0 = {0.f,0.f,0.f,0.f}, aH1 = {0.f,0.f,0.f,0.f};
    floatx4 aL0 = {0.f,0.f,0.f,0.f}, aL1 = {0.f,0.f,0.f,0.f};
    const int n0 = 16 * ntA + ln;
    const char* yrow = smc + BY_Y + n0 * YROW;
    #pragma unroll
    for (int ks = 0; ks < NKA; ++ks) {
      const int kb = (32 * ks + 8 * q) * 2;
      const half8 b0 = *(const half8*)(yrow + SWZ(n0, kb));
      if (ks & 1) {
        aH1 = MFMA16(DhF[ks], b0, aH1, 0, 0, 0);
        aL1 = MFMA16(DlF[ks], b0, aL1, 0, 0, 0);
      } else {
        aH0 = MFMA16(DhF[ks], b0, aH0, 0, 0, 0);
        aL0 = MFMA16(DlF[ks], b0, aL0, 0, 0, 0);
      }
    }
    float* Rb = outR + b * TDIM * NCOL + dh * DHALF;
    const int c = n0;
    if (c < DHALF) {
      const int t0 = 16 * mtA + 4 * q;
      #pragma unroll
      for (int r = 0; r < 4; ++r) {
        const int t = t0 + r;
        if (t < TDIM)
          Rb[t * NCOL + c] = (aH0[r] + aH1[r]) + (aL0[r] + aL1[r]);
      }
    }
  }
}

// ---------------- launch --------------------------------------------------------------

extern "C" void kernel_launch(void* const* d_in, const int* in_sizes, int n_in,
                              void* d_out, int out_size, void* d_ws, size_t ws_size,
                              hipStream_t stream) {
  const float* x     = (const float*)d_in[0];   // (256, 36, 50)
  const float* rho   = (const float*)d_in[1];   // (80,)
  const float* theta = (const float*)d_in[2];   // (80,)

  float* out    = (float*)d_out;
  float* outC   = out;                              // 256*161*50
  float* outDic = out + 256 * PDIM * NCOL;          // 36*161
  float* outR   = outDic + TDIM * PDIM;             // 256*36*50

  hipLaunchKernelGGL(dan_kernel, dim3(512), dim3(384), LDS_TOTAL, stream,
                     x, rho, theta, outC, outDic, outR);
}